// Round 1
// baseline (273.446 us; speedup 1.0000x reference)
//
#include <hip/hip_runtime.h>

// TPLoss: pred [B,N] fp32, labels [B,N] int32 (0/1) -> scalar fp32
//   s = sigmoid(pred); TP = sum(s*l); SP = sum(s); SL = sum(l)
//   denom = 1 - N + SP + SL - 2*TP ;  loss = -mean_b(TP/denom)
//
// R1-R5 history: per-CU read rate pinned ~4.3-6 B/cy across schedules,
// occupancy, and NT loads -> VGPR-return fill-tracking cap theory (TCP
// miss queue ~30 lines @ ~900cy). R6 single-variable test: move BOTH
// streams to the global_load_lds DMA path (returns to LDS, not VGPRs).
// If the DMA path has a separate/deeper outstanding budget, per-CU read
// approaches the ~10 B/cy/CU copy-regime rate -> rows kernel ~50us.
// Per-wave private double-buffer, counted vmcnt(4) (never drain to 0 in
// the steady loop), lgkmcnt(0) before issue as WAR guard on buffer reuse.

typedef float f4v __attribute__((ext_vector_type(4)));
typedef int   i4v __attribute__((ext_vector_type(4)));

#define BDIM 256
#define WPB 4               // waves per block, one row each
#define ROWS 4096
#define COLS 8192
#define CB   2048           // chunk bytes per stream (2 x 1KB DMA per stream)
#define NCHUNK ((COLS * 4) / CB)   // 16 chunks per row

__device__ __forceinline__ void ld16_lds(const void* g, void* l) {
    // 16B/lane x 64 lanes = 1KB per instruction, LDS dest = uniform base + lane*16
    __builtin_amdgcn_global_load_lds(
        (const __attribute__((address_space(1))) void*)g,
        (__attribute__((address_space(3))) void*)l, 16, 0, 0);
}

__global__ __launch_bounds__(BDIM) void tploss_rows(
    const float* __restrict__ pred,
    const int* __restrict__ labels,
    float* __restrict__ row_out)
{
    // per wave: P0,P1,L0,L1 buffers of CB bytes -> 8KB/wave, 32KB/block
    __shared__ __align__(16) char lds[WPB * 4 * CB];

    const int lane = threadIdx.x & 63;
    const int wv   = threadIdx.x >> 6;
    const int row  = blockIdx.x * WPB + wv;

    char* const base = lds + wv * 4 * CB;
    char* const P0 = base;
    char* const P1 = base + CB;
    char* const L0 = base + 2 * CB;
    char* const L1 = base + 3 * CB;

    const char* gp = (const char*)(pred   + (size_t)row * COLS);
    const char* gl = (const char*)(labels + (size_t)row * COLS);
    const int lo = lane * 16;

    float sp = 0.0f;   // sum sigmoid
    float tp = 0.0f;   // sum sigmoid*label
    int   sl = 0;      // sum label (exact)

    // consume one 2KB chunk (8 elements/lane) from LDS buffers
    auto consume = [&](const char* Pc, const char* Lc) {
        const f4v* pv = (const f4v*)Pc;
        const i4v* lv = (const i4v*)Lc;
#pragma unroll
        for (int s = 0; s < 2; ++s) {
            f4v v = pv[s * 64 + lane];   // ds_read_b128
            i4v q = lv[s * 64 + lane];   // ds_read_b128
            f4v r;
            // sigmoid via v_exp + v_rcp (~2^-21 rel err; rcp(inf)=0 correct limit)
            r.x = __builtin_amdgcn_rcpf(1.0f + __expf(-v.x));
            r.y = __builtin_amdgcn_rcpf(1.0f + __expf(-v.y));
            r.z = __builtin_amdgcn_rcpf(1.0f + __expf(-v.z));
            r.w = __builtin_amdgcn_rcpf(1.0f + __expf(-v.w));
            sp += (r.x + r.y) + (r.z + r.w);
            tp = fmaf(r.x, (float)q.x, tp);
            tp = fmaf(r.y, (float)q.y, tp);
            tp = fmaf(r.z, (float)q.z, tp);
            tp = fmaf(r.w, (float)q.w, tp);
            sl += (q.x + q.y) + (q.z + q.w);
        }
    };

    // prologue: chunk 0 -> buffer 0
    ld16_lds(gp + lo,        P0);
    ld16_lds(gp + 1024 + lo, P0 + 1024);
    ld16_lds(gl + lo,        L0);
    ld16_lds(gl + 1024 + lo, L0 + 1024);

#pragma unroll
    for (int c = 0; c < NCHUNK - 1; ++c) {
        // fully unrolled -> buffer selection is compile-time constant
        char* const Pn = ((c + 1) & 1) ? P1 : P0;
        char* const Ln = ((c + 1) & 1) ? L1 : L0;
        const char* const Pc = (c & 1) ? P1 : P0;
        const char* const Lc = (c & 1) ? L1 : L0;
        const char* const gpc = gp + (size_t)(c + 1) * CB;
        const char* const glc = gl + (size_t)(c + 1) * CB;

        // WAR guard: previous chunk's ds_reads retired before DMA overwrites buffer
        asm volatile("s_waitcnt lgkmcnt(0)" ::: "memory");

        // issue chunk c+1 (4 x 1KB DMA); these stay in flight across compute
        ld16_lds(gpc + lo,        Pn);
        ld16_lds(gpc + 1024 + lo, Pn + 1024);
        ld16_lds(glc + lo,        Ln);
        ld16_lds(glc + 1024 + lo, Ln + 1024);

        // counted wait: chunk c's 4 loads done, chunk c+1's 4 still outstanding
        asm volatile("s_waitcnt vmcnt(4)" ::: "memory");

        consume(Pc, Lc);
    }

    // epilogue: last chunk (NCHUNK-1 = 15, odd -> buffer 1)
    asm volatile("s_waitcnt vmcnt(0)" ::: "memory");
    consume(P1, L1);

    float slf = (float)sl;

    // wave-64 butterfly; no LDS dependence, no __syncthreads
#pragma unroll
    for (int off = 32; off > 0; off >>= 1) {
        sp  += __shfl_down(sp,  off, 64);
        tp  += __shfl_down(tp,  off, 64);
        slf += __shfl_down(slf, off, 64);
    }

    if (lane == 0) {
        float denom = 1.0f - (float)COLS + sp + slf - 2.0f * tp;
        row_out[row] = tp / denom;   // one plain store per row, no atomics
    }
}

__global__ __launch_bounds__(BDIM) void tploss_reduce(
    const float* __restrict__ row_out,
    float* __restrict__ out)
{
    const int tid = threadIdx.x;
    float s = 0.0f;
#pragma unroll
    for (int i = 0; i < ROWS / BDIM; ++i)
        s += row_out[i * BDIM + tid];

#pragma unroll
    for (int off = 32; off > 0; off >>= 1)
        s += __shfl_down(s, off, 64);

    __shared__ float sw[BDIM / 64];
    const int wave = tid >> 6;
    const int lane = tid & 63;
    if (lane == 0) sw[wave] = s;
    __syncthreads();

    if (tid == 0) {
        float tot = (sw[0] + sw[1]) + (sw[2] + sw[3]);
        out[0] = -tot * (1.0f / (float)ROWS);
    }
}

extern "C" void kernel_launch(void* const* d_in, const int* in_sizes, int n_in,
                              void* d_out, int out_size, void* d_ws, size_t ws_size,
                              hipStream_t stream) {
    const float* pred   = (const float*)d_in[0];
    const int*   labels = (const int*)d_in[1];
    float* row_out = (float*)d_ws;   // 4096 floats; fully overwritten each call

    tploss_rows<<<ROWS / WPB, BDIM, 0, stream>>>(pred, labels, row_out);
    tploss_reduce<<<1, BDIM, 0, stream>>>(row_out, (float*)d_out);
}

// Round 2
// 248.835 us; speedup vs baseline: 1.0989x; 1.0989x over previous
//
#include <hip/hip_runtime.h>

// TPLoss: pred [B,N] fp32, labels [B,N] int32 (0/1) -> scalar fp32
//   s = sigmoid(pred); TP = sum(s*l); SP = sum(s); SL = sum(l)
//   denom = 1 - N + SP + SL - 2*TP ;  loss = -mean_b(TP/denom)
//
// R1-R6: per-CU read pinned ~3.5-3.7 TB/s across schedules, occupancy,
// NT loads, and the global_load_lds DMA path (R6: WORSE, 98us - shares
// the same miss machinery). Common factor of all six: row-per-wave
// layout -> ~5400 scattered concurrent streams -> DRAM row-buffer /
// translation thrash. R7 single-variable test: STEP-MAJOR decomposition.
// All 4096 resident waves sweep one contiguous 32MB slab per k-step
// (group g = k*4096 + wave). Same 16-batched NT load schedule as R0.
// Per-group in-wave reduce -> float2 partial per (row,quarter) into ws.

typedef float f4v __attribute__((ext_vector_type(4)));
typedef int   i4v __attribute__((ext_vector_type(4)));

#define BDIM 256
#define GRID 1024            // 4096 waves, all co-resident (16 waves/CU)
#define ROWS 4096
#define COLS 8192
#define NGROUP 16384         // 8KB pred-groups (2048 floats = 1/4 row)
#define NWAVE (GRID * (BDIM / 64))
#define GPW (NGROUP / NWAVE) // 4 groups per wave

__global__ __launch_bounds__(BDIM, 4) void tploss_part(
    const float* __restrict__ pred,
    const int* __restrict__ labels,
    float2* __restrict__ ws)
{
    const int lane = threadIdx.x & 63;
    const int w    = blockIdx.x * (BDIM / 64) + (threadIdx.x >> 6);

    for (int k = 0; k < GPW; ++k) {
        const int g = k * NWAVE + w;   // step-major: dense 32MB chip-wide window
        const f4v* pg = (const f4v*)(pred   + (size_t)g * 2048) + lane;
        const i4v* lg = (const i4v*)(labels + (size_t)g * 2048) + lane;

        // 16 batched nontemporal loads (R0's proven schedule): 8KB + 8KB
        f4v p[8];
        i4v q[8];
#pragma unroll
        for (int i = 0; i < 8; ++i) p[i] = __builtin_nontemporal_load(&pg[i * 64]);
#pragma unroll
        for (int i = 0; i < 8; ++i) q[i] = __builtin_nontemporal_load(&lg[i * 64]);
#pragma unroll
        for (int i = 0; i < 8; ++i) asm volatile("" : "+v"(p[i]));
#pragma unroll
        for (int i = 0; i < 8; ++i) asm volatile("" : "+v"(q[i]));

        float sp = 0.0f;
        float tp = 0.0f;
        int   sl = 0;
#pragma unroll
        for (int i = 0; i < 8; ++i) {
            f4v v = p[i];
            f4v r;
            // sigmoid via v_exp + v_rcp (~2^-21 rel err; rcp(inf)=0 correct limit)
            r.x = __builtin_amdgcn_rcpf(1.0f + __expf(-v.x));
            r.y = __builtin_amdgcn_rcpf(1.0f + __expf(-v.y));
            r.z = __builtin_amdgcn_rcpf(1.0f + __expf(-v.z));
            r.w = __builtin_amdgcn_rcpf(1.0f + __expf(-v.w));
            sp += (r.x + r.y) + (r.z + r.w);
            tp = fmaf(r.x, (float)q[i].x, tp);
            tp = fmaf(r.y, (float)q[i].y, tp);
            tp = fmaf(r.z, (float)q[i].z, tp);
            tp = fmaf(r.w, (float)q[i].w, tp);
            sl += (q[i].x + q[i].y) + (q[i].z + q[i].w);
        }

        // wave-64 butterfly over the group's 2048 elements
        float slf = (float)sl;
#pragma unroll
        for (int off = 32; off > 0; off >>= 1) {
            sp  += __shfl_down(sp,  off, 64);
            tp  += __shfl_down(tp,  off, 64);
            slf += __shfl_down(slf, off, 64);
        }

        if (lane == 0) {
            float2 o;
            o.x = tp;        // partial TP for (row g/4, quarter g%4)
            o.y = sp + slf;  // partial SP+SL
            ws[g] = o;       // plain store, every ws entry written each call
        }
    }
}

__global__ __launch_bounds__(1024) void tploss_final(
    const float2* __restrict__ ws,
    float* __restrict__ out)
{
    const int t = threadIdx.x;
    const f4v* w4 = (const f4v*)ws;   // [tp0,c0,tp1,c1] pairs

    float acc = 0.0f;
#pragma unroll
    for (int rr = 0; rr < ROWS / 1024; ++rr) {
        const int r = rr * 1024 + t;
        f4v a = w4[r * 2 + 0];   // quarters 0,1
        f4v b = w4[r * 2 + 1];   // quarters 2,3
        float tp = (a.x + a.z) + (b.x + b.z);
        float c  = (a.y + a.w) + (b.y + b.w);
        float denom = 1.0f - (float)COLS + c - 2.0f * tp;
        acc += tp / denom;
    }

#pragma unroll
    for (int off = 32; off > 0; off >>= 1)
        acc += __shfl_down(acc, off, 64);

    __shared__ float sw[1024 / 64];
    const int wave = t >> 6;
    const int lane = t & 63;
    if (lane == 0) sw[wave] = acc;
    __syncthreads();

    if (t == 0) {
        float tot = 0.0f;
#pragma unroll
        for (int i = 0; i < 1024 / 64; ++i) tot += sw[i];
        out[0] = -tot * (1.0f / (float)ROWS);
    }
}

extern "C" void kernel_launch(void* const* d_in, const int* in_sizes, int n_in,
                              void* d_out, int out_size, void* d_ws, size_t ws_size,
                              hipStream_t stream) {
    const float* pred   = (const float*)d_in[0];
    const int*   labels = (const int*)d_in[1];
    float2* ws = (float2*)d_ws;   // 16384 float2 = 128KB; fully overwritten each call

    tploss_part<<<GRID, BDIM, 0, stream>>>(pred, labels, ws);
    tploss_final<<<1, 1024, 0, stream>>>(ws, (float*)d_out);
}